// Round 4
// baseline (1499.225 us; speedup 1.0000x reference)
//
#include <hip/hip_runtime.h>

#define N_NODES 50000
#define N_EDGES 800000
#define F 64
#define SCAN_BLOCKS ((N_NODES + 255) / 256)   // 196
#define TSLOTS 64                              // nodes per transform tile

// ---------------- bf16 helpers (storage-only; all math fp32) ----------------

__device__ __forceinline__ float bf2f(unsigned short u) {
    union { unsigned int i; float f; } c; c.i = ((unsigned int)u) << 16; return c.f;
}
__device__ __forceinline__ unsigned short f2bf(float f) {   // round-nearest-even
    union { float f; unsigned int i; } c; c.f = f;
    unsigned int r = c.i + 0x7FFF + ((c.i >> 16) & 1);
    return (unsigned short)(r >> 16);
}

// ---------------- CSR build ----------------

__global__ void hist_kernel(const int* __restrict__ dst, int* __restrict__ deg, int n) {
    int e = blockIdx.x * blockDim.x + threadIdx.x;
    if (e < n) atomicAdd(&deg[dst[e]], 1);
}

__global__ __launch_bounds__(256) void scan_a(const int* __restrict__ deg,
                                              int* __restrict__ local_scan,
                                              int* __restrict__ partials, int n) {
    int i = blockIdx.x * 256 + threadIdx.x;
    int lane = threadIdx.x & 63, wv = threadIdx.x >> 6;
    int v = (i < n) ? deg[i] : 0;
    int s = v;
    #pragma unroll
    for (int off = 1; off < 64; off <<= 1) {
        int t = __shfl_up(s, off);
        if (lane >= off) s += t;
    }
    __shared__ int wsum[4];
    if (lane == 63) wsum[wv] = s;
    __syncthreads();
    if (threadIdx.x == 0) {
        int a = 0;
        #pragma unroll
        for (int w = 0; w < 4; ++w) { int t = wsum[w]; wsum[w] = a; a += t; }
        partials[blockIdx.x] = a;
    }
    __syncthreads();
    s += wsum[wv];
    if (i < n) local_scan[i] = s;
}

__global__ __launch_bounds__(256) void scan_b(int* __restrict__ partials, int nb) {
    int i = threadIdx.x;
    int lane = threadIdx.x & 63, wv = threadIdx.x >> 6;
    int v = (i < nb) ? partials[i] : 0;
    int s = v;
    #pragma unroll
    for (int off = 1; off < 64; off <<= 1) {
        int t = __shfl_up(s, off);
        if (lane >= off) s += t;
    }
    __shared__ int wsum[4];
    if (lane == 63) wsum[wv] = s;
    __syncthreads();
    if (threadIdx.x == 0) {
        int a = 0;
        #pragma unroll
        for (int w = 0; w < 4; ++w) { int t = wsum[w]; wsum[w] = a; a += t; }
    }
    __syncthreads();
    s += wsum[wv];
    if (i < nb) partials[i] = s - v;
}

__global__ __launch_bounds__(256) void scan_c(const int* __restrict__ local_scan,
                                              const int* __restrict__ partials,
                                              const int* __restrict__ deg,
                                              int* __restrict__ row_ptr,
                                              int* __restrict__ cursor, int n) {
    int i = blockIdx.x * 256 + threadIdx.x;
    if (i >= n) return;
    int fin = local_scan[i] + partials[blockIdx.x];
    row_ptr[i + 1] = fin;
    cursor[i] = fin - deg[i];
    if (i == 0) row_ptr[0] = 0;
}

__global__ void fill_kernel(const int* __restrict__ src, const int* __restrict__ dst,
                            int* __restrict__ cursor, unsigned short* __restrict__ csr16, int n) {
    int e = blockIdx.x * blockDim.x + threadIdx.x;
    if (e < n) {
        int d = dst[e];
        int pos = atomicAdd(&cursor[d], 1);
        csr16[pos] = (unsigned short)src[e];   // src < 50000 < 65536
    }
}

// ---------------- fp32 -> bf16 row conversion (x only; h1 written bf16 directly) ------

__global__ __launch_bounds__(256) void cvt_kernel(const float4* __restrict__ in,
                                                  ushort4* __restrict__ out, int n4) {
    int i = blockIdx.x * blockDim.x + threadIdx.x;
    if (i >= n4) return;
    float4 v = in[i];
    ushort4 o;
    o.x = f2bf(v.x); o.y = f2bf(v.y); o.z = f2bf(v.z); o.w = f2bf(v.w);
    out[i] = o;
}

// ------------- aggregation: wave/node, 4 groups x 16 lanes x ushort4, 4 chains -------

__global__ __launch_bounds__(256) void aggregate_kernel(
        const ushort4* __restrict__ xh, const int* __restrict__ row_ptr,
        const unsigned short* __restrict__ csr16, float4* __restrict__ agg4, int n_nodes) {
    int wave = threadIdx.x >> 6;
    int lane = threadIdx.x & 63;
    int node = blockIdx.x * 4 + wave;
    if (node >= n_nodes) return;
    int g   = lane >> 4;    // edge group
    int sub = lane & 15;    // ushort4 (4 feats) within 64-feat row
    int beg = row_ptr[node], end = row_ptr[node + 1];
    float4 a0 = make_float4(0.f,0.f,0.f,0.f), a1 = a0, a2 = a0, a3 = a0;
    int i = beg + g;
    for (; i + 12 < end; i += 16) {   // 4 independent gather chains
        int i0 = csr16[i], i1 = csr16[i+4], i2 = csr16[i+8], i3 = csr16[i+12];
        ushort4 v0 = xh[i0 * 16 + sub];
        ushort4 v1 = xh[i1 * 16 + sub];
        ushort4 v2 = xh[i2 * 16 + sub];
        ushort4 v3 = xh[i3 * 16 + sub];
        a0.x += bf2f(v0.x); a0.y += bf2f(v0.y); a0.z += bf2f(v0.z); a0.w += bf2f(v0.w);
        a1.x += bf2f(v1.x); a1.y += bf2f(v1.y); a1.z += bf2f(v1.z); a1.w += bf2f(v1.w);
        a2.x += bf2f(v2.x); a2.y += bf2f(v2.y); a2.z += bf2f(v2.z); a2.w += bf2f(v2.w);
        a3.x += bf2f(v3.x); a3.y += bf2f(v3.y); a3.z += bf2f(v3.z); a3.w += bf2f(v3.w);
    }
    for (; i < end; i += 4) {
        ushort4 v0 = xh[csr16[i] * 16 + sub];
        a0.x += bf2f(v0.x); a0.y += bf2f(v0.y); a0.z += bf2f(v0.z); a0.w += bf2f(v0.w);
    }
    float4 s = make_float4(a0.x + a1.x + a2.x + a3.x,
                           a0.y + a1.y + a2.y + a3.y,
                           a0.z + a1.z + a2.z + a3.z,
                           a0.w + a1.w + a2.w + a3.w);
    #pragma unroll
    for (int off = 16; off <= 32; off <<= 1) {
        s.x += __shfl_xor(s.x, off);
        s.y += __shfl_xor(s.y, off);
        s.z += __shfl_xor(s.z, off);
        s.w += __shfl_xor(s.w, off);
    }
    if (g == 0) {
        int deg = end - beg;
        float inv = (deg > 0) ? (1.0f / (float)deg) : 0.f;
        s.x *= inv; s.y *= inv; s.z *= inv; s.w *= inv;
        agg4[node * 16 + sub] = s;
    }
}

// ---------------- transform: relu(x@Ws + agg@Wn + b); 64-node tiles, 4 nodes/thread --
// self-features arrive bf16; agg fp32; math fp32.
// out_bf != null  -> store relu result as bf16 rows (layer 1/2 hidden)
// pout   != null  -> fused layer-3 projection: p = h.Wn3, q = h.Ws3 (h never stored)

__global__ __launch_bounds__(256) void transform_kernel(
        const ushort4* __restrict__ xh, const float4* __restrict__ agg4,
        const float4* __restrict__ Ws4, const float4* __restrict__ Wn4,
        const float* __restrict__ b,
        ushort4* __restrict__ out_bf, int n_nodes,
        const float* __restrict__ Ws3, const float* __restrict__ Wn3,
        float* __restrict__ pout, float* __restrict__ qout) {
    __shared__ float4 sWs[F * 16];       // 16 KB
    __shared__ float4 sWn[F * 16];       // 16 KB
    __shared__ float  sx[TSLOTS][F + 4];
    __shared__ float  sa[TSLOTS][F + 4];

    for (int i = threadIdx.x; i < F * 16; i += 256) {
        sWs[i] = Ws4[i];
        sWn[i] = Wn4[i];
    }

    int j4 = threadIdx.x & 15;
    int sg = threadIdx.x >> 4;
    float4 bias = ((const float4*)b)[j4];
    float4 w3n = make_float4(0.f,0.f,0.f,0.f);
    float4 w3s = w3n;
    if (pout) {
        w3n = ((const float4*)Wn3)[j4];
        w3s = ((const float4*)Ws3)[j4];
    }
    int ntiles = (n_nodes + TSLOTS - 1) / TSLOTS;

    for (int tile = blockIdx.x; tile < ntiles; tile += gridDim.x) {
        int base = tile * TSLOTS;
        __syncthreads();
        for (int t = threadIdx.x; t < TSLOTS * 16; t += 256) {
            int slot = t >> 4, c = t & 15;
            int node = base + slot;
            float4 va = make_float4(0.f,0.f,0.f,0.f);
            float4 vx = va;
            if (node < n_nodes) {
                ushort4 u = xh[node * 16 + c];
                vx = make_float4(bf2f(u.x), bf2f(u.y), bf2f(u.z), bf2f(u.w));
                va = agg4[node * 16 + c];
            }
            *(float4*)&sx[slot][c * 4] = vx;
            *(float4*)&sa[slot][c * 4] = va;
        }
        __syncthreads();

        float4 acc[4];
        #pragma unroll
        for (int s = 0; s < 4; ++s) acc[s] = bias;
        #pragma unroll
        for (int k = 0; k < F; ++k) {
            float4 ws = sWs[k * 16 + j4];
            float4 wn = sWn[k * 16 + j4];
            #pragma unroll
            for (int s = 0; s < 4; ++s) {
                float xv = sx[sg * 4 + s][k];
                float av = sa[sg * 4 + s][k];
                acc[s].x += xv * ws.x + av * wn.x;
                acc[s].y += xv * ws.y + av * wn.y;
                acc[s].z += xv * ws.z + av * wn.z;
                acc[s].w += xv * ws.w + av * wn.w;
            }
        }

        #pragma unroll
        for (int s = 0; s < 4; ++s) {
            int node = base + sg * 4 + s;
            if (node < n_nodes) {
                float4 h;
                h.x = fmaxf(acc[s].x, 0.f); h.y = fmaxf(acc[s].y, 0.f);
                h.z = fmaxf(acc[s].z, 0.f); h.w = fmaxf(acc[s].w, 0.f);
                if (pout) {
                    float pp = h.x * w3n.x + h.y * w3n.y + h.z * w3n.z + h.w * w3n.w;
                    float qq = h.x * w3s.x + h.y * w3s.y + h.z * w3s.z + h.w * w3s.w;
                    #pragma unroll
                    for (int off = 1; off < 16; off <<= 1) {
                        pp += __shfl_xor(pp, off);
                        qq += __shfl_xor(qq, off);
                    }
                    if (j4 == 0) { pout[node] = pp; qout[node] = qq; }
                } else {
                    ushort4 o;
                    o.x = f2bf(h.x); o.y = f2bf(h.y); o.z = f2bf(h.z); o.w = f2bf(h.w);
                    out_bf[node * 16 + j4] = o;
                }
            }
        }
    }
}

// ---------------- final: out = q + mean_agg(p) + b3, 16 lanes per node ----------------

__global__ __launch_bounds__(256) void final_kernel(
        const int* __restrict__ row_ptr, const unsigned short* __restrict__ csr16,
        const float* __restrict__ p, const float* __restrict__ q,
        const float* __restrict__ b3, float* __restrict__ out, int n_nodes) {
    int grp = threadIdx.x >> 4;
    int ln  = threadIdx.x & 15;
    int node = blockIdx.x * 16 + grp;
    if (node >= n_nodes) return;
    int beg = row_ptr[node], end = row_ptr[node + 1];
    float s = 0.f;
    for (int i = beg + ln; i < end; i += 16) s += p[csr16[i]];
    #pragma unroll
    for (int off = 1; off < 16; off <<= 1) s += __shfl_xor(s, off);
    if (ln == 0) {
        int deg = end - beg;
        float inv = (deg > 0) ? (1.0f / (float)deg) : 0.f;
        out[node] = q[node] + s * inv + b3[0];
    }
}

// ---------------- launch ----------------

extern "C" void kernel_launch(void* const* d_in, const int* in_sizes, int n_in,
                              void* d_out, int out_size, void* d_ws, size_t ws_size,
                              hipStream_t stream) {
    const float* x   = (const float*)d_in[0];
    const int*   src = (const int*)d_in[1];
    const int*   dst = (const int*)d_in[2];
    const float* Ws1 = (const float*)d_in[3];
    const float* Wn1 = (const float*)d_in[4];
    const float* b1  = (const float*)d_in[5];
    const float* Ws2 = (const float*)d_in[6];
    const float* Wn2 = (const float*)d_in[7];
    const float* b2  = (const float*)d_in[8];
    const float* Ws3 = (const float*)d_in[9];
    const float* Wn3 = (const float*)d_in[10];
    const float* b3  = (const float*)d_in[11];
    float* out = (float*)d_out;

    char* ws = (char*)d_ws;
    size_t cur = 0;
    auto alloc = [&](size_t bytes) -> void* {
        void* p = ws + cur;
        cur += (bytes + 255) & ~(size_t)255;
        return p;
    };

    int*            deg      = (int*)  alloc(N_NODES * sizeof(int));
    int*            lscan    = (int*)  alloc(N_NODES * sizeof(int));
    int*            partials = (int*)  alloc(256 * sizeof(int));
    int*            row_ptr  = (int*)  alloc((N_NODES + 1) * sizeof(int));
    int*            cursor   = (int*)  alloc(N_NODES * sizeof(int));
    unsigned short* csr16    = (unsigned short*)alloc(N_EDGES * sizeof(unsigned short));
    ushort4*        xh       = (ushort4*)alloc((size_t)N_NODES * F * 2);   // bf16 x
    ushort4*        h1h      = (ushort4*)alloc((size_t)N_NODES * F * 2);   // bf16 h1
    float*          agg      = (float*)alloc((size_t)N_NODES * F * sizeof(float));
    float*          p        = (float*)alloc(N_NODES * sizeof(float));
    float*          q        = (float*)alloc(N_NODES * sizeof(float));

    // CSR build
    hipMemsetAsync(deg, 0, N_NODES * sizeof(int), stream);
    hist_kernel<<<(N_EDGES + 255) / 256, 256, 0, stream>>>(dst, deg, N_EDGES);
    scan_a<<<SCAN_BLOCKS, 256, 0, stream>>>(deg, lscan, partials, N_NODES);
    scan_b<<<1, 256, 0, stream>>>(partials, SCAN_BLOCKS);
    scan_c<<<SCAN_BLOCKS, 256, 0, stream>>>(lscan, partials, deg, row_ptr, cursor, N_NODES);
    fill_kernel<<<(N_EDGES + 255) / 256, 256, 0, stream>>>(src, dst, cursor, csr16, N_EDGES);

    // x -> bf16
    cvt_kernel<<<(N_NODES * 16 + 255) / 256, 256, 0, stream>>>((const float4*)x, xh, N_NODES * 16);

    int agg_grid = (N_NODES + 3) / 4;
    int tf_grid  = (N_NODES + TSLOTS - 1) / TSLOTS;   // 782

    // layer 1
    aggregate_kernel<<<agg_grid, 256, 0, stream>>>(xh, row_ptr, csr16, (float4*)agg, N_NODES);
    transform_kernel<<<tf_grid, 256, 0, stream>>>(
        xh, (const float4*)agg, (const float4*)Ws1, (const float4*)Wn1, b1,
        h1h, N_NODES, nullptr, nullptr, nullptr, nullptr);
    // layer 2 (+ fused layer-3 projection)
    aggregate_kernel<<<agg_grid, 256, 0, stream>>>(h1h, row_ptr, csr16, (float4*)agg, N_NODES);
    transform_kernel<<<tf_grid, 256, 0, stream>>>(
        h1h, (const float4*)agg, (const float4*)Ws2, (const float4*)Wn2, b2,
        nullptr, N_NODES, Ws3, Wn3, p, q);
    // layer 3: aggregate scalars
    final_kernel<<<(N_NODES + 15) / 16, 256, 0, stream>>>(row_ptr, csr16, p, q, b3, out, N_NODES);
}

// Round 5
// 302.346 us; speedup vs baseline: 4.9586x; 4.9586x over previous
//
#include <hip/hip_runtime.h>

#define N_NODES 50000
#define N_EDGES 800000
#define F 64
#define SCAN_BLOCKS ((N_NODES + 255) / 256)   // 196
#define TSLOTS 64                              // nodes per transform tile

// ---------------- bf16 helpers (storage-only; all math fp32) ----------------

__device__ __forceinline__ float bf2f(unsigned short u) {
    union { unsigned int i; float f; } c; c.i = ((unsigned int)u) << 16; return c.f;
}
__device__ __forceinline__ unsigned short f2bf(float f) {   // round-nearest-even
    union { float f; unsigned int i; } c; c.f = f;
    unsigned int r = c.i + 0x7FFF + ((c.i >> 16) & 1);
    return (unsigned short)(r >> 16);
}

// ---------------- CSR build ----------------

__global__ void hist_kernel(const int* __restrict__ dst, int* __restrict__ deg, int n) {
    int e = blockIdx.x * blockDim.x + threadIdx.x;
    if (e < n) atomicAdd(&deg[dst[e]], 1);
}

__global__ __launch_bounds__(256) void scan_a(const int* __restrict__ deg,
                                              int* __restrict__ local_scan,
                                              int* __restrict__ partials, int n) {
    int i = blockIdx.x * 256 + threadIdx.x;
    int lane = threadIdx.x & 63, wv = threadIdx.x >> 6;
    int v = (i < n) ? deg[i] : 0;
    int s = v;
    #pragma unroll
    for (int off = 1; off < 64; off <<= 1) {
        int t = __shfl_up(s, off);
        if (lane >= off) s += t;
    }
    __shared__ int wsum[4];
    if (lane == 63) wsum[wv] = s;
    __syncthreads();
    if (threadIdx.x == 0) {
        int a = 0;
        #pragma unroll
        for (int w = 0; w < 4; ++w) { int t = wsum[w]; wsum[w] = a; a += t; }
        partials[blockIdx.x] = a;
    }
    __syncthreads();
    s += wsum[wv];
    if (i < n) local_scan[i] = s;
}

__global__ __launch_bounds__(256) void scan_b(int* __restrict__ partials, int nb) {
    int i = threadIdx.x;
    int lane = threadIdx.x & 63, wv = threadIdx.x >> 6;
    int v = (i < nb) ? partials[i] : 0;
    int s = v;
    #pragma unroll
    for (int off = 1; off < 64; off <<= 1) {
        int t = __shfl_up(s, off);
        if (lane >= off) s += t;
    }
    __shared__ int wsum[4];
    if (lane == 63) wsum[wv] = s;
    __syncthreads();
    if (threadIdx.x == 0) {
        int a = 0;
        #pragma unroll
        for (int w = 0; w < 4; ++w) { int t = wsum[w]; wsum[w] = a; a += t; }
    }
    __syncthreads();
    s += wsum[wv];
    if (i < nb) partials[i] = s - v;
}

__global__ __launch_bounds__(256) void scan_c(const int* __restrict__ local_scan,
                                              const int* __restrict__ partials,
                                              const int* __restrict__ deg,
                                              int* __restrict__ row_ptr,
                                              int* __restrict__ cursor, int n) {
    int i = blockIdx.x * 256 + threadIdx.x;
    if (i >= n) return;
    int fin = local_scan[i] + partials[blockIdx.x];
    row_ptr[i + 1] = fin;
    cursor[i] = fin - deg[i];
    if (i == 0) row_ptr[0] = 0;
}

__global__ void fill_kernel(const int* __restrict__ src, const int* __restrict__ dst,
                            int* __restrict__ cursor, unsigned short* __restrict__ csr16, int n) {
    int e = blockIdx.x * blockDim.x + threadIdx.x;
    if (e < n) {
        int d = dst[e];
        int pos = atomicAdd(&cursor[d], 1);
        csr16[pos] = (unsigned short)src[e];   // src < 50000 < 65536
    }
}

// ---------------- fp32 -> bf16 row conversion (for the gather path only) -------------

__global__ __launch_bounds__(256) void cvt_kernel(const float4* __restrict__ in,
                                                  ushort4* __restrict__ out, int n4) {
    int i = blockIdx.x * blockDim.x + threadIdx.x;
    if (i >= n4) return;
    float4 v = in[i];
    ushort4 o;
    o.x = f2bf(v.x); o.y = f2bf(v.y); o.z = f2bf(v.z); o.w = f2bf(v.w);
    out[i] = o;
}

// ------------- aggregation: wave/node, 4 groups x 16 lanes x ushort4, 4 chains -------

__global__ __launch_bounds__(256) void aggregate_kernel(
        const ushort4* __restrict__ xh, const int* __restrict__ row_ptr,
        const unsigned short* __restrict__ csr16, float4* __restrict__ agg4, int n_nodes) {
    int wave = threadIdx.x >> 6;
    int lane = threadIdx.x & 63;
    int node = blockIdx.x * 4 + wave;
    if (node >= n_nodes) return;
    int g   = lane >> 4;    // edge group
    int sub = lane & 15;    // ushort4 (4 feats) within 64-feat row
    int beg = row_ptr[node], end = row_ptr[node + 1];
    float4 a0 = make_float4(0.f,0.f,0.f,0.f), a1 = a0, a2 = a0, a3 = a0;
    int i = beg + g;
    for (; i + 12 < end; i += 16) {   // 4 independent gather chains
        int i0 = csr16[i], i1 = csr16[i+4], i2 = csr16[i+8], i3 = csr16[i+12];
        ushort4 v0 = xh[i0 * 16 + sub];
        ushort4 v1 = xh[i1 * 16 + sub];
        ushort4 v2 = xh[i2 * 16 + sub];
        ushort4 v3 = xh[i3 * 16 + sub];
        a0.x += bf2f(v0.x); a0.y += bf2f(v0.y); a0.z += bf2f(v0.z); a0.w += bf2f(v0.w);
        a1.x += bf2f(v1.x); a1.y += bf2f(v1.y); a1.z += bf2f(v1.z); a1.w += bf2f(v1.w);
        a2.x += bf2f(v2.x); a2.y += bf2f(v2.y); a2.z += bf2f(v2.z); a2.w += bf2f(v2.w);
        a3.x += bf2f(v3.x); a3.y += bf2f(v3.y); a3.z += bf2f(v3.z); a3.w += bf2f(v3.w);
    }
    for (; i < end; i += 4) {
        ushort4 v0 = xh[csr16[i] * 16 + sub];
        a0.x += bf2f(v0.x); a0.y += bf2f(v0.y); a0.z += bf2f(v0.z); a0.w += bf2f(v0.w);
    }
    float4 s = make_float4(a0.x + a1.x + a2.x + a3.x,
                           a0.y + a1.y + a2.y + a3.y,
                           a0.z + a1.z + a2.z + a3.z,
                           a0.w + a1.w + a2.w + a3.w);
    #pragma unroll
    for (int off = 16; off <= 32; off <<= 1) {
        s.x += __shfl_xor(s.x, off);
        s.y += __shfl_xor(s.y, off);
        s.z += __shfl_xor(s.z, off);
        s.w += __shfl_xor(s.w, off);
    }
    if (g == 0) {
        int deg = end - beg;
        float inv = (deg > 0) ? (1.0f / (float)deg) : 0.f;
        s.x *= inv; s.y *= inv; s.z *= inv; s.w *= inv;
        agg4[node * 16 + sub] = s;
    }
}

// ---------------- transform (exact R3 known-good): fp32 in, fp32 out or fused p,q ----

__global__ __launch_bounds__(256) void transform_kernel(
        const float4* __restrict__ x4, const float4* __restrict__ agg4,
        const float4* __restrict__ Ws4, const float4* __restrict__ Wn4,
        const float* __restrict__ b, float* __restrict__ out,
        int n_nodes, int do_relu,
        const float* __restrict__ Ws3, const float* __restrict__ Wn3,
        float* __restrict__ pout, float* __restrict__ qout) {
    __shared__ float4 sWs[F * 16];       // 16 KB
    __shared__ float4 sWn[F * 16];       // 16 KB
    __shared__ float  sx[TSLOTS][F + 4];
    __shared__ float  sa[TSLOTS][F + 4];

    for (int i = threadIdx.x; i < F * 16; i += 256) {
        sWs[i] = Ws4[i];
        sWn[i] = Wn4[i];
    }

    int j4 = threadIdx.x & 15;
    int sg = threadIdx.x >> 4;
    float4 bias = ((const float4*)b)[j4];
    float4 w3n = make_float4(0.f, 0.f, 0.f, 0.f);
    float4 w3s = make_float4(0.f, 0.f, 0.f, 0.f);
    if (pout) {
        w3n = ((const float4*)Wn3)[j4];
        w3s = ((const float4*)Ws3)[j4];
    }
    int ntiles = (n_nodes + TSLOTS - 1) / TSLOTS;

    for (int tile = blockIdx.x; tile < ntiles; tile += gridDim.x) {
        int base = tile * TSLOTS;
        __syncthreads();   // protect sx/sa reuse (first pass also covers W staging)
        for (int t = threadIdx.x; t < TSLOTS * 16; t += 256) {
            int slot = t >> 4, c = t & 15;
            int node = base + slot;
            float4 vx = make_float4(0.f, 0.f, 0.f, 0.f);
            float4 va = vx;
            if (node < n_nodes) { vx = x4[node * 16 + c]; va = agg4[node * 16 + c]; }
            *(float4*)&sx[slot][c * 4] = vx;
            *(float4*)&sa[slot][c * 4] = va;
        }
        __syncthreads();

        float4 acc[4];
        #pragma unroll
        for (int s = 0; s < 4; ++s) acc[s] = bias;
        #pragma unroll
        for (int k = 0; k < F; ++k) {
            float4 ws = sWs[k * 16 + j4];
            float4 wn = sWn[k * 16 + j4];
            #pragma unroll
            for (int s = 0; s < 4; ++s) {
                float xv = sx[sg * 4 + s][k];
                float av = sa[sg * 4 + s][k];
                acc[s].x += xv * ws.x + av * wn.x;
                acc[s].y += xv * ws.y + av * wn.y;
                acc[s].z += xv * ws.z + av * wn.z;
                acc[s].w += xv * ws.w + av * wn.w;
            }
        }

        if (pout) {
            #pragma unroll
            for (int s = 0; s < 4; ++s) {
                int node = base + sg * 4 + s;
                if (node < n_nodes) {  // uniform across the 16-lane group
                    float4 h;
                    h.x = fmaxf(acc[s].x, 0.f); h.y = fmaxf(acc[s].y, 0.f);
                    h.z = fmaxf(acc[s].z, 0.f); h.w = fmaxf(acc[s].w, 0.f);
                    float pp = h.x * w3n.x + h.y * w3n.y + h.z * w3n.z + h.w * w3n.w;
                    float qq = h.x * w3s.x + h.y * w3s.y + h.z * w3s.z + h.w * w3s.w;
                    #pragma unroll
                    for (int off = 1; off < 16; off <<= 1) {
                        pp += __shfl_xor(pp, off);
                        qq += __shfl_xor(qq, off);
                    }
                    if (j4 == 0) { pout[node] = pp; qout[node] = qq; }
                }
            }
        } else {
            #pragma unroll
            for (int s = 0; s < 4; ++s) {
                int node = base + sg * 4 + s;
                if (node < n_nodes) {
                    float4 v = acc[s];
                    if (do_relu) {
                        v.x = fmaxf(v.x, 0.f); v.y = fmaxf(v.y, 0.f);
                        v.z = fmaxf(v.z, 0.f); v.w = fmaxf(v.w, 0.f);
                    }
                    *(float4*)&out[node * F + j4 * 4] = v;
                }
            }
        }
    }
}

// ---------------- final: out = q + mean_agg(p) + b3, 16 lanes per node ----------------

__global__ __launch_bounds__(256) void final_kernel(
        const int* __restrict__ row_ptr, const unsigned short* __restrict__ csr16,
        const float* __restrict__ p, const float* __restrict__ q,
        const float* __restrict__ b3, float* __restrict__ out, int n_nodes) {
    int grp = threadIdx.x >> 4;
    int ln  = threadIdx.x & 15;
    int node = blockIdx.x * 16 + grp;
    if (node >= n_nodes) return;
    int beg = row_ptr[node], end = row_ptr[node + 1];
    float s = 0.f;
    for (int i = beg + ln; i < end; i += 16) s += p[csr16[i]];
    #pragma unroll
    for (int off = 1; off < 16; off <<= 1) s += __shfl_xor(s, off);
    if (ln == 0) {
        int deg = end - beg;
        float inv = (deg > 0) ? (1.0f / (float)deg) : 0.f;
        out[node] = q[node] + s * inv + b3[0];
    }
}

// ---------------- launch ----------------

extern "C" void kernel_launch(void* const* d_in, const int* in_sizes, int n_in,
                              void* d_out, int out_size, void* d_ws, size_t ws_size,
                              hipStream_t stream) {
    const float* x   = (const float*)d_in[0];
    const int*   src = (const int*)d_in[1];
    const int*   dst = (const int*)d_in[2];
    const float* Ws1 = (const float*)d_in[3];
    const float* Wn1 = (const float*)d_in[4];
    const float* b1  = (const float*)d_in[5];
    const float* Ws2 = (const float*)d_in[6];
    const float* Wn2 = (const float*)d_in[7];
    const float* b2  = (const float*)d_in[8];
    const float* Ws3 = (const float*)d_in[9];
    const float* Wn3 = (const float*)d_in[10];
    const float* b3  = (const float*)d_in[11];
    float* out = (float*)d_out;

    char* ws = (char*)d_ws;
    size_t cur = 0;
    auto alloc = [&](size_t bytes) -> void* {
        void* p = ws + cur;
        cur += (bytes + 255) & ~(size_t)255;
        return p;
    };

    int*            deg      = (int*)  alloc(N_NODES * sizeof(int));
    int*            lscan    = (int*)  alloc(N_NODES * sizeof(int));
    int*            partials = (int*)  alloc(256 * sizeof(int));
    int*            row_ptr  = (int*)  alloc((N_NODES + 1) * sizeof(int));
    int*            cursor   = (int*)  alloc(N_NODES * sizeof(int));
    unsigned short* csr16    = (unsigned short*)alloc(N_EDGES * sizeof(unsigned short));
    ushort4*        xh       = (ushort4*)alloc((size_t)N_NODES * F * 2);   // bf16 gather copy
    float*          h1       = (float*)alloc((size_t)N_NODES * F * sizeof(float));
    float*          agg      = (float*)alloc((size_t)N_NODES * F * sizeof(float));
    float*          p        = (float*)alloc(N_NODES * sizeof(float));
    float*          q        = (float*)alloc(N_NODES * sizeof(float));

    // CSR build
    hipMemsetAsync(deg, 0, N_NODES * sizeof(int), stream);
    hist_kernel<<<(N_EDGES + 255) / 256, 256, 0, stream>>>(dst, deg, N_EDGES);
    scan_a<<<SCAN_BLOCKS, 256, 0, stream>>>(deg, lscan, partials, N_NODES);
    scan_b<<<1, 256, 0, stream>>>(partials, SCAN_BLOCKS);
    scan_c<<<SCAN_BLOCKS, 256, 0, stream>>>(lscan, partials, deg, row_ptr, cursor, N_NODES);
    fill_kernel<<<(N_EDGES + 255) / 256, 256, 0, stream>>>(src, dst, cursor, csr16, N_EDGES);

    int agg_grid = (N_NODES + 3) / 4;
    int tf_grid  = (N_NODES + TSLOTS - 1) / TSLOTS;   // 782
    int cvt_grid = (N_NODES * 16 + 255) / 256;

    // layer 1: x -> bf16 copy for gather; aggregate; transform (fp32 in/out)
    cvt_kernel<<<cvt_grid, 256, 0, stream>>>((const float4*)x, xh, N_NODES * 16);
    aggregate_kernel<<<agg_grid, 256, 0, stream>>>(xh, row_ptr, csr16, (float4*)agg, N_NODES);
    transform_kernel<<<tf_grid, 256, 0, stream>>>(
        (const float4*)x, (const float4*)agg, (const float4*)Ws1, (const float4*)Wn1,
        b1, h1, N_NODES, 1, nullptr, nullptr, nullptr, nullptr);
    // layer 2: h1 -> bf16 copy for gather; aggregate; transform + fused layer-3 projection
    cvt_kernel<<<cvt_grid, 256, 0, stream>>>((const float4*)h1, xh, N_NODES * 16);
    aggregate_kernel<<<agg_grid, 256, 0, stream>>>(xh, row_ptr, csr16, (float4*)agg, N_NODES);
    transform_kernel<<<tf_grid, 256, 0, stream>>>(
        (const float4*)h1, (const float4*)agg, (const float4*)Ws2, (const float4*)Wn2,
        b2, nullptr, N_NODES, 1, Ws3, Wn3, p, q);
    // layer 3: aggregate scalars
    final_kernel<<<(N_NODES + 15) / 16, 256, 0, stream>>>(row_ptr, csr16, p, q, b3, out, N_NODES);
}

// Round 6
// 252.126 us; speedup vs baseline: 5.9463x; 1.1992x over previous
//
#include <hip/hip_runtime.h>

#define N_NODES 50000
#define N_EDGES 800000
#define F 64
#define SCAN_BLOCKS ((N_NODES + 255) / 256)   // 196
#define NTILES (N_NODES / 16)                  // 3125 (50000 = 3125*16 exactly)

typedef __attribute__((ext_vector_type(8))) short short8;   // 8 bf16 (4 VGPRs)
typedef __attribute__((ext_vector_type(4))) float f32x4;    // MFMA accumulator

union frag16 { uint4 u; short8 s; };

// ---------------- bf16 helpers (storage-only; all math fp32/MFMA) ----------------

__device__ __forceinline__ float bf2f(unsigned short u) {
    union { unsigned int i; float f; } c; c.i = ((unsigned int)u) << 16; return c.f;
}
__device__ __forceinline__ unsigned short f2bf(float f) {   // round-nearest-even
    union { float f; unsigned int i; } c; c.f = f;
    unsigned int r = c.i + 0x7FFF + ((c.i >> 16) & 1);
    return (unsigned short)(r >> 16);
}

// ---------------- CSR build ----------------

__global__ void hist_kernel(const int* __restrict__ dst, int* __restrict__ deg, int n) {
    int e = blockIdx.x * blockDim.x + threadIdx.x;
    if (e < n) atomicAdd(&deg[dst[e]], 1);
}

__global__ __launch_bounds__(256) void scan_a(const int* __restrict__ deg,
                                              int* __restrict__ local_scan,
                                              int* __restrict__ partials, int n) {
    int i = blockIdx.x * 256 + threadIdx.x;
    int lane = threadIdx.x & 63, wv = threadIdx.x >> 6;
    int v = (i < n) ? deg[i] : 0;
    int s = v;
    #pragma unroll
    for (int off = 1; off < 64; off <<= 1) {
        int t = __shfl_up(s, off);
        if (lane >= off) s += t;
    }
    __shared__ int wsum[4];
    if (lane == 63) wsum[wv] = s;
    __syncthreads();
    if (threadIdx.x == 0) {
        int a = 0;
        #pragma unroll
        for (int w = 0; w < 4; ++w) { int t = wsum[w]; wsum[w] = a; a += t; }
        partials[blockIdx.x] = a;
    }
    __syncthreads();
    s += wsum[wv];
    if (i < n) local_scan[i] = s;
}

__global__ __launch_bounds__(256) void scan_b(int* __restrict__ partials, int nb) {
    int i = threadIdx.x;
    int lane = threadIdx.x & 63, wv = threadIdx.x >> 6;
    int v = (i < nb) ? partials[i] : 0;
    int s = v;
    #pragma unroll
    for (int off = 1; off < 64; off <<= 1) {
        int t = __shfl_up(s, off);
        if (lane >= off) s += t;
    }
    __shared__ int wsum[4];
    if (lane == 63) wsum[wv] = s;
    __syncthreads();
    if (threadIdx.x == 0) {
        int a = 0;
        #pragma unroll
        for (int w = 0; w < 4; ++w) { int t = wsum[w]; wsum[w] = a; a += t; }
    }
    __syncthreads();
    s += wsum[wv];
    if (i < nb) partials[i] = s - v;
}

__global__ __launch_bounds__(256) void scan_c(const int* __restrict__ local_scan,
                                              const int* __restrict__ partials,
                                              const int* __restrict__ deg,
                                              int* __restrict__ row_ptr,
                                              int* __restrict__ cursor, int n) {
    int i = blockIdx.x * 256 + threadIdx.x;
    if (i >= n) return;
    int fin = local_scan[i] + partials[blockIdx.x];
    row_ptr[i + 1] = fin;
    cursor[i] = fin - deg[i];
    if (i == 0) row_ptr[0] = 0;
}

__global__ void fill_kernel(const int* __restrict__ src, const int* __restrict__ dst,
                            int* __restrict__ cursor, unsigned short* __restrict__ csr16, int n) {
    int e = blockIdx.x * blockDim.x + threadIdx.x;
    if (e < n) {
        int d = dst[e];
        int pos = atomicAdd(&cursor[d], 1);
        csr16[pos] = (unsigned short)src[e];   // src < 50000 < 65536
    }
}

// ---------------- fp32 -> bf16 row conversion (x only; h1 written bf16 directly) -----

__global__ __launch_bounds__(256) void cvt_kernel(const float4* __restrict__ in,
                                                  ushort4* __restrict__ out, int n4) {
    int i = blockIdx.x * blockDim.x + threadIdx.x;
    if (i >= n4) return;
    float4 v = in[i];
    ushort4 o;
    o.x = f2bf(v.x); o.y = f2bf(v.y); o.z = f2bf(v.z); o.w = f2bf(v.w);
    out[i] = o;
}

// ---------------- W prep: fp32 W[k][n] -> bf16 W^T[n][k] for 4 matrices --------------

__global__ __launch_bounds__(256) void prep_w(const float* __restrict__ W0,
                                              const float* __restrict__ W1,
                                              const float* __restrict__ W2,
                                              const float* __restrict__ W3,
                                              unsigned short* __restrict__ out) {
    int idx = blockIdx.x * 256 + threadIdx.x;
    if (idx >= 4 * F * F) return;
    int m = idx >> 12;
    int e = idx & 4095;
    int n = e >> 6, k = e & 63;
    const float* W = (m == 0) ? W0 : (m == 1) ? W1 : (m == 2) ? W2 : W3;
    out[m * F * F + n * F + k] = f2bf(W[k * F + n]);
}

// ------------- aggregation: wave/node, 4 groups x 16 lanes x ushort4, 4 chains -------
// in: bf16 rows; out: bf16 rows (fp32 accumulate inside)

__global__ __launch_bounds__(256) void aggregate_kernel(
        const ushort4* __restrict__ xh, const int* __restrict__ row_ptr,
        const unsigned short* __restrict__ csr16, ushort4* __restrict__ aggh, int n_nodes) {
    int wave = threadIdx.x >> 6;
    int lane = threadIdx.x & 63;
    int node = blockIdx.x * 4 + wave;
    if (node >= n_nodes) return;
    int g   = lane >> 4;
    int sub = lane & 15;
    int beg = row_ptr[node], end = row_ptr[node + 1];
    float4 a0 = make_float4(0.f,0.f,0.f,0.f), a1 = a0, a2 = a0, a3 = a0;
    int i = beg + g;
    for (; i + 12 < end; i += 16) {   // 4 independent gather chains
        int i0 = csr16[i], i1 = csr16[i+4], i2 = csr16[i+8], i3 = csr16[i+12];
        ushort4 v0 = xh[i0 * 16 + sub];
        ushort4 v1 = xh[i1 * 16 + sub];
        ushort4 v2 = xh[i2 * 16 + sub];
        ushort4 v3 = xh[i3 * 16 + sub];
        a0.x += bf2f(v0.x); a0.y += bf2f(v0.y); a0.z += bf2f(v0.z); a0.w += bf2f(v0.w);
        a1.x += bf2f(v1.x); a1.y += bf2f(v1.y); a1.z += bf2f(v1.z); a1.w += bf2f(v1.w);
        a2.x += bf2f(v2.x); a2.y += bf2f(v2.y); a2.z += bf2f(v2.z); a2.w += bf2f(v2.w);
        a3.x += bf2f(v3.x); a3.y += bf2f(v3.y); a3.z += bf2f(v3.z); a3.w += bf2f(v3.w);
    }
    for (; i < end; i += 4) {
        ushort4 v0 = xh[csr16[i] * 16 + sub];
        a0.x += bf2f(v0.x); a0.y += bf2f(v0.y); a0.z += bf2f(v0.z); a0.w += bf2f(v0.w);
    }
    float4 s = make_float4(a0.x + a1.x + a2.x + a3.x,
                           a0.y + a1.y + a2.y + a3.y,
                           a0.z + a1.z + a2.z + a3.z,
                           a0.w + a1.w + a2.w + a3.w);
    #pragma unroll
    for (int off = 16; off <= 32; off <<= 1) {
        s.x += __shfl_xor(s.x, off);
        s.y += __shfl_xor(s.y, off);
        s.z += __shfl_xor(s.z, off);
        s.w += __shfl_xor(s.w, off);
    }
    if (g == 0) {
        int deg = end - beg;
        float inv = (deg > 0) ? (1.0f / (float)deg) : 0.f;
        ushort4 o;
        o.x = f2bf(s.x * inv); o.y = f2bf(s.y * inv);
        o.z = f2bf(s.z * inv); o.w = f2bf(s.w * inv);
        aggh[node * 16 + sub] = o;
    }
}

// ---------------- MFMA transform: h = relu(x@Ws + agg@Wn + b) ------------------------
// One wave per 16-node m-tile, no LDS. A-frags straight from global bf16 rows
// (A[m=lane&15][k=(lane>>4)*8+j]); B-frags from pre-transposed bf16 W^T[n][k]
// (B[k][n], n=lane&15). C/D: col=lane&15, row=(lane>>4)*4+reg.
// out_bf != null -> store h as bf16 rows.  pout != null -> fused p=h.Wn3, q=h.Ws3.

__global__ __launch_bounds__(256) void mfma_transform(
        const uint4* __restrict__ xh, const uint4* __restrict__ aggh,
        const uint4* __restrict__ Wst, const uint4* __restrict__ Wnt,
        const float* __restrict__ b,
        unsigned short* __restrict__ out_bf,
        const float* __restrict__ Ws3, const float* __restrict__ Wn3,
        float* __restrict__ pout, float* __restrict__ qout, int ntiles) {
    int wv   = threadIdx.x >> 6;
    int lane = threadIdx.x & 63;
    int tile = blockIdx.x * 4 + wv;
    if (tile >= ntiles) return;
    int lo = lane & 15, hi = lane >> 4;

    // B fragments: ws[kt][jt], wn[kt][jt]  (uniform work per wave; L2-resident)
    frag16 ws[2][4], wn[2][4];
    #pragma unroll
    for (int kt = 0; kt < 2; ++kt)
        #pragma unroll
        for (int jt = 0; jt < 4; ++jt) {
            int n = jt * 16 + lo;
            ws[kt][jt].u = Wst[n * 8 + kt * 4 + hi];
            wn[kt][jt].u = Wnt[n * 8 + kt * 4 + hi];
        }

    float bias_s[4];
    #pragma unroll
    for (int jt = 0; jt < 4; ++jt) bias_s[jt] = b[jt * 16 + lo];
    float w3n_s[4], w3s_s[4];
    if (pout) {
        #pragma unroll
        for (int jt = 0; jt < 4; ++jt) {
            w3n_s[jt] = Wn3[jt * 16 + lo];
            w3s_s[jt] = Ws3[jt * 16 + lo];
        }
    }

    int base = tile * 16;
    int node = base + lo;

    frag16 ax[2], aa[2];
    #pragma unroll
    for (int kt = 0; kt < 2; ++kt) {
        ax[kt].u = xh[node * 8 + kt * 4 + hi];
        aa[kt].u = aggh[node * 8 + kt * 4 + hi];
    }

    f32x4 acc[4];
    #pragma unroll
    for (int jt = 0; jt < 4; ++jt)
        acc[jt] = f32x4{bias_s[jt], bias_s[jt], bias_s[jt], bias_s[jt]};

    #pragma unroll
    for (int kt = 0; kt < 2; ++kt)
        #pragma unroll
        for (int jt = 0; jt < 4; ++jt) {
            acc[jt] = __builtin_amdgcn_mfma_f32_16x16x32_bf16(ax[kt].s, ws[kt][jt].s, acc[jt], 0, 0, 0);
            acc[jt] = __builtin_amdgcn_mfma_f32_16x16x32_bf16(aa[kt].s, wn[kt][jt].s, acc[jt], 0, 0, 0);
        }

    if (out_bf) {
        #pragma unroll
        for (int jt = 0; jt < 4; ++jt)
            #pragma unroll
            for (int r = 0; r < 4; ++r) {
                float h = fmaxf(acc[jt][r], 0.f);
                out_bf[(base + hi * 4 + r) * F + jt * 16 + lo] = f2bf(h);
            }
    } else {
        #pragma unroll
        for (int r = 0; r < 4; ++r) {
            float pr = 0.f, qr = 0.f;
            #pragma unroll
            for (int jt = 0; jt < 4; ++jt) {
                float h = fmaxf(acc[jt][r], 0.f);
                pr += h * w3n_s[jt];
                qr += h * w3s_s[jt];
            }
            #pragma unroll
            for (int off = 1; off < 16; off <<= 1) {
                pr += __shfl_xor(pr, off);
                qr += __shfl_xor(qr, off);
            }
            if (lo == 0) {
                pout[base + hi * 4 + r] = pr;
                qout[base + hi * 4 + r] = qr;
            }
        }
    }
}

// ---------------- final: out = q + mean_agg(p) + b3, 16 lanes per node ----------------

__global__ __launch_bounds__(256) void final_kernel(
        const int* __restrict__ row_ptr, const unsigned short* __restrict__ csr16,
        const float* __restrict__ p, const float* __restrict__ q,
        const float* __restrict__ b3, float* __restrict__ out, int n_nodes) {
    int grp = threadIdx.x >> 4;
    int ln  = threadIdx.x & 15;
    int node = blockIdx.x * 16 + grp;
    if (node >= n_nodes) return;
    int beg = row_ptr[node], end = row_ptr[node + 1];
    float s = 0.f;
    for (int i = beg + ln; i < end; i += 16) s += p[csr16[i]];
    #pragma unroll
    for (int off = 1; off < 16; off <<= 1) s += __shfl_xor(s, off);
    if (ln == 0) {
        int deg = end - beg;
        float inv = (deg > 0) ? (1.0f / (float)deg) : 0.f;
        out[node] = q[node] + s * inv + b3[0];
    }
}

// ---------------- launch ----------------

extern "C" void kernel_launch(void* const* d_in, const int* in_sizes, int n_in,
                              void* d_out, int out_size, void* d_ws, size_t ws_size,
                              hipStream_t stream) {
    const float* x   = (const float*)d_in[0];
    const int*   src = (const int*)d_in[1];
    const int*   dst = (const int*)d_in[2];
    const float* Ws1 = (const float*)d_in[3];
    const float* Wn1 = (const float*)d_in[4];
    const float* b1  = (const float*)d_in[5];
    const float* Ws2 = (const float*)d_in[6];
    const float* Wn2 = (const float*)d_in[7];
    const float* b2  = (const float*)d_in[8];
    const float* Ws3 = (const float*)d_in[9];
    const float* Wn3 = (const float*)d_in[10];
    const float* b3  = (const float*)d_in[11];
    float* out = (float*)d_out;

    char* ws = (char*)d_ws;
    size_t cur = 0;
    auto alloc = [&](size_t bytes) -> void* {
        void* p = ws + cur;
        cur += (bytes + 255) & ~(size_t)255;
        return p;
    };

    int*            deg      = (int*)  alloc(N_NODES * sizeof(int));
    int*            lscan    = (int*)  alloc(N_NODES * sizeof(int));
    int*            partials = (int*)  alloc(256 * sizeof(int));
    int*            row_ptr  = (int*)  alloc((N_NODES + 1) * sizeof(int));
    int*            cursor   = (int*)  alloc(N_NODES * sizeof(int));
    unsigned short* csr16    = (unsigned short*)alloc(N_EDGES * sizeof(unsigned short));
    unsigned short* xh       = (unsigned short*)alloc((size_t)N_NODES * F * 2);  // bf16 x
    unsigned short* h1h      = (unsigned short*)alloc((size_t)N_NODES * F * 2);  // bf16 h1
    unsigned short* aggh     = (unsigned short*)alloc((size_t)N_NODES * F * 2);  // bf16 agg
    unsigned short* Wt       = (unsigned short*)alloc(4 * F * F * 2);            // bf16 W^T x4
    float*          p        = (float*)alloc(N_NODES * sizeof(float));
    float*          q        = (float*)alloc(N_NODES * sizeof(float));

    unsigned short* Wst1 = Wt;
    unsigned short* Wnt1 = Wt + F * F;
    unsigned short* Wst2 = Wt + 2 * F * F;
    unsigned short* Wnt2 = Wt + 3 * F * F;

    // CSR build
    hipMemsetAsync(deg, 0, N_NODES * sizeof(int), stream);
    hist_kernel<<<(N_EDGES + 255) / 256, 256, 0, stream>>>(dst, deg, N_EDGES);
    scan_a<<<SCAN_BLOCKS, 256, 0, stream>>>(deg, lscan, partials, N_NODES);
    scan_b<<<1, 256, 0, stream>>>(partials, SCAN_BLOCKS);
    scan_c<<<SCAN_BLOCKS, 256, 0, stream>>>(lscan, partials, deg, row_ptr, cursor, N_NODES);
    fill_kernel<<<(N_EDGES + 255) / 256, 256, 0, stream>>>(src, dst, cursor, csr16, N_EDGES);

    // weight transpose+cast, x -> bf16
    prep_w<<<(4 * F * F + 255) / 256, 256, 0, stream>>>(Ws1, Wn1, Ws2, Wn2, Wt);
    cvt_kernel<<<(N_NODES * 16 + 255) / 256, 256, 0, stream>>>(
        (const float4*)x, (ushort4*)xh, N_NODES * 16);

    int agg_grid = (N_NODES + 3) / 4;
    int tf_grid  = (NTILES + 3) / 4;   // 782

    // layer 1
    aggregate_kernel<<<agg_grid, 256, 0, stream>>>(
        (const ushort4*)xh, row_ptr, csr16, (ushort4*)aggh, N_NODES);
    mfma_transform<<<tf_grid, 256, 0, stream>>>(
        (const uint4*)xh, (const uint4*)aggh, (const uint4*)Wst1, (const uint4*)Wnt1,
        b1, h1h, nullptr, nullptr, nullptr, nullptr, NTILES);
    // layer 2 (+ fused layer-3 projection)
    aggregate_kernel<<<agg_grid, 256, 0, stream>>>(
        (const ushort4*)h1h, row_ptr, csr16, (ushort4*)aggh, N_NODES);
    mfma_transform<<<tf_grid, 256, 0, stream>>>(
        (const uint4*)h1h, (const uint4*)aggh, (const uint4*)Wst2, (const uint4*)Wnt2,
        b2, nullptr, Ws3, Wn3, p, q, NTILES);
    // layer 3: aggregate scalars
    final_kernel<<<(N_NODES + 15) / 16, 256, 0, stream>>>(row_ptr, csr16, p, q, b3, out, N_NODES);
}

// Round 7
// 200.416 us; speedup vs baseline: 7.4806x; 1.2580x over previous
//
#include <hip/hip_runtime.h>

#define N_NODES 50000
#define N_EDGES 800000
#define F 64
#define NTILES (N_NODES / 16)                  // 3125 (50000 = 3125*16 exactly)

#define BNODES 128                             // nodes per bucket
#define NB ((N_NODES + BNODES - 1) / BNODES)   // 391 buckets
#define EPB 3200                               // edges per bin_scatter block
#define SCAT_BLOCKS (N_EDGES / EPB)            // 250 (exact)

typedef __attribute__((ext_vector_type(8))) short short8;   // 8 bf16 (4 VGPRs)
typedef __attribute__((ext_vector_type(4))) float f32x4;    // MFMA accumulator

union frag16 { uint4 u; short8 s; };

// ---------------- bf16 helpers (storage-only; all math fp32/MFMA) ----------------

__device__ __forceinline__ float bf2f(unsigned short u) {
    union { unsigned int i; float f; } c; c.i = ((unsigned int)u) << 16; return c.f;
}
__device__ __forceinline__ unsigned short f2bf(float f) {   // round-nearest-even
    union { float f; unsigned int i; } c; c.f = f;
    unsigned int r = c.i + 0x7FFF + ((c.i >> 16) & 1);
    return (unsigned short)(r >> 16);
}

// ---------------- binned CSR build ----------------
// packed edge: src (bits 0-15) | dst_local (bits 16-22) | bucket (bits 23-31)

__global__ __launch_bounds__(256) void bin_count(const int* __restrict__ dst,
                                                 int* __restrict__ bcnt, int n) {
    __shared__ int lc[NB];
    for (int i = threadIdx.x; i < NB; i += 256) lc[i] = 0;
    __syncthreads();
    for (int e = blockIdx.x * 256 + threadIdx.x; e < n; e += gridDim.x * 256)
        atomicAdd(&lc[dst[e] >> 7], 1);
    __syncthreads();
    for (int i = threadIdx.x; i < NB; i += 256)
        if (lc[i]) atomicAdd(&bcnt[i], lc[i]);
}

__global__ __launch_bounds__(512) void bucket_scan(const int* __restrict__ bcnt,
                                                   int* __restrict__ bbase,
                                                   int* __restrict__ bcur) {
    __shared__ int s[512];
    int i = threadIdx.x;
    int v = (i < NB) ? bcnt[i] : 0;
    s[i] = v;
    __syncthreads();
    for (int off = 1; off < 512; off <<= 1) {
        int t = (i >= off) ? s[i - off] : 0;
        __syncthreads();
        s[i] += t;
        __syncthreads();
    }
    if (i < NB) { int b = s[i] - v; bbase[i] = b; bcur[i] = b; }
}

__global__ __launch_bounds__(512) void bin_scatter(const int* __restrict__ src,
                                                   const int* __restrict__ dst,
                                                   int* __restrict__ bcur,
                                                   unsigned int* __restrict__ binned, int n) {
    __shared__ int lcnt[NB];
    __shared__ int scan[512];
    __shared__ int gbase[NB];   // global_reserved - local_excl (so dest = gbase[b] + stage_idx)
    __shared__ int lcur[NB];
    __shared__ unsigned int staged[EPB];
    int tid = threadIdx.x;
    int e0 = blockIdx.x * EPB;
    int e1 = min(n, e0 + EPB);
    for (int i = tid; i < NB; i += 512) lcnt[i] = 0;
    __syncthreads();
    for (int i = e0 + tid; i < e1; i += 512)
        atomicAdd(&lcnt[dst[i] >> 7], 1);
    __syncthreads();
    int v = (tid < NB) ? lcnt[tid] : 0;
    scan[tid] = v;
    __syncthreads();
    for (int off = 1; off < 512; off <<= 1) {
        int t = (tid >= off) ? scan[tid - off] : 0;
        __syncthreads();
        scan[tid] += t;
        __syncthreads();
    }
    if (tid < NB) {
        int excl = scan[tid] - v;           // local exclusive scan
        int resv = (v > 0) ? atomicAdd(&bcur[tid], v) : 0;
        gbase[tid] = resv - excl;
        lcur[tid] = excl;
    }
    __syncthreads();
    for (int i = e0 + tid; i < e1; i += 512) {
        int d = dst[i];
        int b = d >> 7;
        int dl = d & 127;
        int posl = atomicAdd(&lcur[b], 1);
        staged[posl] = (unsigned)src[i] | ((unsigned)dl << 16) | ((unsigned)b << 23);
    }
    __syncthreads();
    int cnt = e1 - e0;
    for (int i = tid; i < cnt; i += 512) {
        unsigned pk = staged[i];
        int b = pk >> 23;
        binned[gbase[b] + i] = pk;   // grouped by bucket -> mostly coalesced
    }
}

// one block per bucket: node counts, local scan, row_ptr + csr16 writes (single-owner lines)
__global__ __launch_bounds__(256) void bucket_build(const unsigned int* __restrict__ binned,
                                                    const int* __restrict__ bbase,
                                                    const int* __restrict__ bcnt,
                                                    int* __restrict__ row_ptr,
                                                    unsigned short* __restrict__ csr16) {
    int b = blockIdx.x;
    int start = bbase[b];
    int cnt = bcnt[b];
    __shared__ int ncnt[BNODES];
    __shared__ int nofs[BNODES];
    __shared__ int ncur[BNODES];
    int tid = threadIdx.x;
    for (int i = tid; i < BNODES; i += 256) ncnt[i] = 0;
    __syncthreads();
    for (int i = tid; i < cnt; i += 256)
        atomicAdd(&ncnt[(binned[start + i] >> 16) & 127], 1);
    __syncthreads();
    if (tid < 128) nofs[tid] = ncnt[tid];
    __syncthreads();
    for (int off = 1; off < 128; off <<= 1) {
        int t = (tid >= off && tid < 128) ? nofs[tid - off] : 0;
        __syncthreads();
        if (tid < 128) nofs[tid] += t;
        __syncthreads();
    }
    if (tid < 128) {
        int excl = nofs[tid] - ncnt[tid];
        ncur[tid] = excl;
        int node = b * BNODES + tid;
        if (node <= N_NODES) row_ptr[node] = start + excl;   // node==N_NODES -> N_EDGES
    }
    __syncthreads();
    for (int i = tid; i < cnt; i += 256) {
        unsigned pk = binned[start + i];
        int dl = (pk >> 16) & 127;
        int pos = start + atomicAdd(&ncur[dl], 1);
        csr16[pos] = (unsigned short)(pk & 0xFFFF);
    }
}

// ---------------- fp32 -> bf16 row conversion (x only; h1 written bf16 directly) -----

__global__ __launch_bounds__(256) void cvt_kernel(const float4* __restrict__ in,
                                                  ushort4* __restrict__ out, int n4) {
    int i = blockIdx.x * blockDim.x + threadIdx.x;
    if (i >= n4) return;
    float4 v = in[i];
    ushort4 o;
    o.x = f2bf(v.x); o.y = f2bf(v.y); o.z = f2bf(v.z); o.w = f2bf(v.w);
    out[i] = o;
}

// ---------------- W prep: fp32 W[k][n] -> bf16 W^T[n][k] for 4 matrices --------------

__global__ __launch_bounds__(256) void prep_w(const float* __restrict__ W0,
                                              const float* __restrict__ W1,
                                              const float* __restrict__ W2,
                                              const float* __restrict__ W3,
                                              unsigned short* __restrict__ out) {
    int idx = blockIdx.x * 256 + threadIdx.x;
    if (idx >= 4 * F * F) return;
    int m = idx >> 12;
    int e = idx & 4095;
    int n = e >> 6, k = e & 63;
    const float* W = (m == 0) ? W0 : (m == 1) ? W1 : (m == 2) ? W2 : W3;
    out[m * F * F + n * F + k] = f2bf(W[k * F + n]);
}

// ------------- aggregation: wave/node, 4 groups x 16 lanes x ushort4, 4 chains -------

__global__ __launch_bounds__(256) void aggregate_kernel(
        const ushort4* __restrict__ xh, const int* __restrict__ row_ptr,
        const unsigned short* __restrict__ csr16, ushort4* __restrict__ aggh, int n_nodes) {
    int wave = threadIdx.x >> 6;
    int lane = threadIdx.x & 63;
    int node = blockIdx.x * 4 + wave;
    if (node >= n_nodes) return;
    int g   = lane >> 4;
    int sub = lane & 15;
    int beg = row_ptr[node], end = row_ptr[node + 1];
    float4 a0 = make_float4(0.f,0.f,0.f,0.f), a1 = a0, a2 = a0, a3 = a0;
    int i = beg + g;
    for (; i + 12 < end; i += 16) {   // 4 independent gather chains
        int i0 = csr16[i], i1 = csr16[i+4], i2 = csr16[i+8], i3 = csr16[i+12];
        ushort4 v0 = xh[i0 * 16 + sub];
        ushort4 v1 = xh[i1 * 16 + sub];
        ushort4 v2 = xh[i2 * 16 + sub];
        ushort4 v3 = xh[i3 * 16 + sub];
        a0.x += bf2f(v0.x); a0.y += bf2f(v0.y); a0.z += bf2f(v0.z); a0.w += bf2f(v0.w);
        a1.x += bf2f(v1.x); a1.y += bf2f(v1.y); a1.z += bf2f(v1.z); a1.w += bf2f(v1.w);
        a2.x += bf2f(v2.x); a2.y += bf2f(v2.y); a2.z += bf2f(v2.z); a2.w += bf2f(v2.w);
        a3.x += bf2f(v3.x); a3.y += bf2f(v3.y); a3.z += bf2f(v3.z); a3.w += bf2f(v3.w);
    }
    for (; i < end; i += 4) {
        ushort4 v0 = xh[csr16[i] * 16 + sub];
        a0.x += bf2f(v0.x); a0.y += bf2f(v0.y); a0.z += bf2f(v0.z); a0.w += bf2f(v0.w);
    }
    float4 s = make_float4(a0.x + a1.x + a2.x + a3.x,
                           a0.y + a1.y + a2.y + a3.y,
                           a0.z + a1.z + a2.z + a3.z,
                           a0.w + a1.w + a2.w + a3.w);
    #pragma unroll
    for (int off = 16; off <= 32; off <<= 1) {
        s.x += __shfl_xor(s.x, off);
        s.y += __shfl_xor(s.y, off);
        s.z += __shfl_xor(s.z, off);
        s.w += __shfl_xor(s.w, off);
    }
    if (g == 0) {
        int deg = end - beg;
        float inv = (deg > 0) ? (1.0f / (float)deg) : 0.f;
        ushort4 o;
        o.x = f2bf(s.x * inv); o.y = f2bf(s.y * inv);
        o.z = f2bf(s.z * inv); o.w = f2bf(s.w * inv);
        aggh[node * 16 + sub] = o;
    }
}

// ---------------- MFMA transform: h = relu(x@Ws + agg@Wn + b) ------------------------

__global__ __launch_bounds__(256) void mfma_transform(
        const uint4* __restrict__ xh, const uint4* __restrict__ aggh,
        const uint4* __restrict__ Wst, const uint4* __restrict__ Wnt,
        const float* __restrict__ b,
        unsigned short* __restrict__ out_bf,
        const float* __restrict__ Ws3, const float* __restrict__ Wn3,
        float* __restrict__ pout, float* __restrict__ qout, int ntiles) {
    int wv   = threadIdx.x >> 6;
    int lane = threadIdx.x & 63;
    int tile = blockIdx.x * 4 + wv;
    if (tile >= ntiles) return;
    int lo = lane & 15, hi = lane >> 4;

    frag16 ws[2][4], wn[2][4];
    #pragma unroll
    for (int kt = 0; kt < 2; ++kt)
        #pragma unroll
        for (int jt = 0; jt < 4; ++jt) {
            int n = jt * 16 + lo;
            ws[kt][jt].u = Wst[n * 8 + kt * 4 + hi];
            wn[kt][jt].u = Wnt[n * 8 + kt * 4 + hi];
        }

    float bias_s[4];
    #pragma unroll
    for (int jt = 0; jt < 4; ++jt) bias_s[jt] = b[jt * 16 + lo];
    float w3n_s[4], w3s_s[4];
    if (pout) {
        #pragma unroll
        for (int jt = 0; jt < 4; ++jt) {
            w3n_s[jt] = Wn3[jt * 16 + lo];
            w3s_s[jt] = Ws3[jt * 16 + lo];
        }
    }

    int base = tile * 16;
    int node = base + lo;

    frag16 ax[2], aa[2];
    #pragma unroll
    for (int kt = 0; kt < 2; ++kt) {
        ax[kt].u = xh[node * 8 + kt * 4 + hi];
        aa[kt].u = aggh[node * 8 + kt * 4 + hi];
    }

    f32x4 acc[4];
    #pragma unroll
    for (int jt = 0; jt < 4; ++jt)
        acc[jt] = f32x4{bias_s[jt], bias_s[jt], bias_s[jt], bias_s[jt]};

    #pragma unroll
    for (int kt = 0; kt < 2; ++kt)
        #pragma unroll
        for (int jt = 0; jt < 4; ++jt) {
            acc[jt] = __builtin_amdgcn_mfma_f32_16x16x32_bf16(ax[kt].s, ws[kt][jt].s, acc[jt], 0, 0, 0);
            acc[jt] = __builtin_amdgcn_mfma_f32_16x16x32_bf16(aa[kt].s, wn[kt][jt].s, acc[jt], 0, 0, 0);
        }

    if (out_bf) {
        #pragma unroll
        for (int jt = 0; jt < 4; ++jt)
            #pragma unroll
            for (int r = 0; r < 4; ++r) {
                float h = fmaxf(acc[jt][r], 0.f);
                out_bf[(base + hi * 4 + r) * F + jt * 16 + lo] = f2bf(h);
            }
    } else {
        #pragma unroll
        for (int r = 0; r < 4; ++r) {
            float pr = 0.f, qr = 0.f;
            #pragma unroll
            for (int jt = 0; jt < 4; ++jt) {
                float h = fmaxf(acc[jt][r], 0.f);
                pr += h * w3n_s[jt];
                qr += h * w3s_s[jt];
            }
            #pragma unroll
            for (int off = 1; off < 16; off <<= 1) {
                pr += __shfl_xor(pr, off);
                qr += __shfl_xor(qr, off);
            }
            if (lo == 0) {
                pout[base + hi * 4 + r] = pr;
                qout[base + hi * 4 + r] = qr;
            }
        }
    }
}

// ---------------- final: out = q + mean_agg(p) + b3, 16 lanes per node ----------------

__global__ __launch_bounds__(256) void final_kernel(
        const int* __restrict__ row_ptr, const unsigned short* __restrict__ csr16,
        const float* __restrict__ p, const float* __restrict__ q,
        const float* __restrict__ b3, float* __restrict__ out, int n_nodes) {
    int grp = threadIdx.x >> 4;
    int ln  = threadIdx.x & 15;
    int node = blockIdx.x * 16 + grp;
    if (node >= n_nodes) return;
    int beg = row_ptr[node], end = row_ptr[node + 1];
    float s = 0.f;
    for (int i = beg + ln; i < end; i += 16) s += p[csr16[i]];
    #pragma unroll
    for (int off = 1; off < 16; off <<= 1) s += __shfl_xor(s, off);
    if (ln == 0) {
        int deg = end - beg;
        float inv = (deg > 0) ? (1.0f / (float)deg) : 0.f;
        out[node] = q[node] + s * inv + b3[0];
    }
}

// ---------------- launch ----------------

extern "C" void kernel_launch(void* const* d_in, const int* in_sizes, int n_in,
                              void* d_out, int out_size, void* d_ws, size_t ws_size,
                              hipStream_t stream) {
    const float* x   = (const float*)d_in[0];
    const int*   src = (const int*)d_in[1];
    const int*   dst = (const int*)d_in[2];
    const float* Ws1 = (const float*)d_in[3];
    const float* Wn1 = (const float*)d_in[4];
    const float* b1  = (const float*)d_in[5];
    const float* Ws2 = (const float*)d_in[6];
    const float* Wn2 = (const float*)d_in[7];
    const float* b2  = (const float*)d_in[8];
    const float* Ws3 = (const float*)d_in[9];
    const float* Wn3 = (const float*)d_in[10];
    const float* b3  = (const float*)d_in[11];
    float* out = (float*)d_out;

    char* ws = (char*)d_ws;
    size_t cur = 0;
    auto alloc = [&](size_t bytes) -> void* {
        void* p = ws + cur;
        cur += (bytes + 255) & ~(size_t)255;
        return p;
    };

    int*            bcnt     = (int*)  alloc(NB * sizeof(int));
    int*            bbase    = (int*)  alloc(NB * sizeof(int));
    int*            bcur     = (int*)  alloc(NB * sizeof(int));
    unsigned int*   binned   = (unsigned int*)alloc((size_t)N_EDGES * sizeof(unsigned int));
    int*            row_ptr  = (int*)  alloc((N_NODES + 1) * sizeof(int));
    unsigned short* csr16    = (unsigned short*)alloc(N_EDGES * sizeof(unsigned short));
    unsigned short* xh       = (unsigned short*)alloc((size_t)N_NODES * F * 2);  // bf16 x
    unsigned short* h1h      = (unsigned short*)alloc((size_t)N_NODES * F * 2);  // bf16 h1
    unsigned short* aggh     = (unsigned short*)alloc((size_t)N_NODES * F * 2);  // bf16 agg
    unsigned short* Wt       = (unsigned short*)alloc(4 * F * F * 2);            // bf16 W^T x4
    float*          p        = (float*)alloc(N_NODES * sizeof(float));
    float*          q        = (float*)alloc(N_NODES * sizeof(float));

    unsigned short* Wst1 = Wt;
    unsigned short* Wnt1 = Wt + F * F;
    unsigned short* Wst2 = Wt + 2 * F * F;
    unsigned short* Wnt2 = Wt + 3 * F * F;

    // binned CSR build
    hipMemsetAsync(bcnt, 0, NB * sizeof(int), stream);
    bin_count<<<256, 256, 0, stream>>>(dst, bcnt, N_EDGES);
    bucket_scan<<<1, 512, 0, stream>>>(bcnt, bbase, bcur);
    bin_scatter<<<SCAT_BLOCKS, 512, 0, stream>>>(src, dst, bcur, binned, N_EDGES);
    bucket_build<<<NB, 256, 0, stream>>>(binned, bbase, bcnt, row_ptr, csr16);

    // weight transpose+cast, x -> bf16
    prep_w<<<(4 * F * F + 255) / 256, 256, 0, stream>>>(Ws1, Wn1, Ws2, Wn2, Wt);
    cvt_kernel<<<(N_NODES * 16 + 255) / 256, 256, 0, stream>>>(
        (const float4*)x, (ushort4*)xh, N_NODES * 16);

    int agg_grid = (N_NODES + 3) / 4;
    int tf_grid  = (NTILES + 3) / 4;   // 782

    // layer 1
    aggregate_kernel<<<agg_grid, 256, 0, stream>>>(
        (const ushort4*)xh, row_ptr, csr16, (ushort4*)aggh, N_NODES);
    mfma_transform<<<tf_grid, 256, 0, stream>>>(
        (const uint4*)xh, (const uint4*)aggh, (const uint4*)Wst1, (const uint4*)Wnt1,
        b1, h1h, nullptr, nullptr, nullptr, nullptr, NTILES);
    // layer 2 (+ fused layer-3 projection)
    aggregate_kernel<<<agg_grid, 256, 0, stream>>>(
        (const ushort4*)h1h, row_ptr, csr16, (ushort4*)aggh, N_NODES);
    mfma_transform<<<tf_grid, 256, 0, stream>>>(
        (const uint4*)h1h, (const uint4*)aggh, (const uint4*)Wst2, (const uint4*)Wnt2,
        b2, nullptr, Ws3, Wn3, p, q, NTILES);
    // layer 3: aggregate scalars
    final_kernel<<<(N_NODES + 15) / 16, 256, 0, stream>>>(row_ptr, csr16, p, q, b3, out, N_NODES);
}